// Round 3
// baseline (730.851 us; speedup 1.0000x reference)
//
#include <hip/hip_runtime.h>
#include <hip/hip_bf16.h>

#define B_ROWS 8192
#define D_DIM  256
#define QB     64
#define KB     64
#define NT     (B_ROWS / KB)
#define ALPHA  0.8f
// TAU * log2(e) = 3.0 * 1.4426950408889634
#define TAU_LOG2E 4.328085122666890f

typedef __attribute__((ext_vector_type(8))) short bf16x8;
typedef __attribute__((ext_vector_type(4))) float f32x4;
typedef __attribute__((ext_vector_type(4))) unsigned short ushort4v;

__device__ inline unsigned short f2bf(float f) {
    unsigned int u = __builtin_bit_cast(unsigned int, f);
    u += 0x7FFF + ((u >> 16) & 1);   // RNE (finite values)
    return (unsigned short)(u >> 16);
}

// ---------------- Kernel A: gather + row-normalize, emit f32 + bf16 copies --
__global__ __launch_bounds__(256) void k_gather_norm(
    const float* __restrict__ ue, const float* __restrict__ ie,
    const int* __restrict__ u, const int* __restrict__ p,
    float* __restrict__ Xf, unsigned short* __restrict__ Xh,
    float* __restrict__ out)
{
    const int b = blockIdx.x * 4 + (threadIdx.x >> 6);   // 0..16383
    const int lane = threadIdx.x & 63;
    if (b == 0 && lane == 0) out[0] = 0.0f;   // init accumulator (d_out is poisoned)
    const int m = b >> 13;
    const int r = b & 8191;
    const float* src = (m == 0) ? (ue + (size_t)u[r] * D_DIM)
                                : (ie + (size_t)p[r] * D_DIM);
    float4 v = ((const float4*)src)[lane];
    float ss = v.x*v.x + v.y*v.y + v.z*v.z + v.w*v.w;
    #pragma unroll
    for (int mask = 32; mask; mask >>= 1) ss += __shfl_xor(ss, mask);
    const float inv = 1.0f / sqrtf(ss);
    v.x *= inv; v.y *= inv; v.z *= inv; v.w *= inv;
    const size_t off = (size_t)(m * B_ROWS + r) * D_DIM + lane * 4;
    *(float4*)(Xf + off) = v;
    ushort4v h = { f2bf(v.x), f2bf(v.y), f2bf(v.z), f2bf(v.w) };
    *(ushort4v*)(Xh + off) = h;
}

// ---------------- Kernel T: bf16 transpose [2][8192][256] -> [2][256][8192] --
__global__ __launch_bounds__(256) void k_transpose(
    const unsigned short* __restrict__ Xh, unsigned short* __restrict__ Xht)
{
    __shared__ unsigned short tile[64 * 84];
    const int bid = blockIdx.x;                // 0..1023
    const int m = bid >> 9;
    const int t = bid & 511;
    const int rt = t >> 2, ct = t & 3;
    const int r0 = rt * 64, c0 = ct * 64;
    const int tid = threadIdx.x;
    const unsigned short* src = Xh + (size_t)m * B_ROWS * D_DIM;
    unsigned short* dst = Xht + (size_t)m * D_DIM * B_ROWS;
    #pragma unroll
    for (int ph = 0; ph < 2; ++ph) {
        const int row = ph * 32 + (tid >> 3);
        const int ch = tid & 7;
        const unsigned short* s = src + (size_t)(r0 + row) * D_DIM + c0 + ch * 8;
        ushort4v a = *(const ushort4v*)s;
        ushort4v b = *(const ushort4v*)(s + 4);
        *(ushort4v*)(&tile[row * 84 + ch * 8]) = a;
        *(ushort4v*)(&tile[row * 84 + ch * 8 + 4]) = b;
    }
    __syncthreads();
    #pragma unroll
    for (int ph = 0; ph < 2; ++ph) {
        const int d = ph * 32 + (tid >> 3);
        const int kc = tid & 7;
        ushort4v lo = { tile[(kc*8+0)*84 + d], tile[(kc*8+1)*84 + d],
                        tile[(kc*8+2)*84 + d], tile[(kc*8+3)*84 + d] };
        ushort4v hi = { tile[(kc*8+4)*84 + d], tile[(kc*8+5)*84 + d],
                        tile[(kc*8+6)*84 + d], tile[(kc*8+7)*84 + d] };
        unsigned short* o = dst + (size_t)(c0 + d) * B_ROWS + r0 + kc * 8;
        *(ushort4v*)o = lo;
        *(ushort4v*)(o + 4) = hi;
    }
}

// ---------------- Kernel B: flash spec-smooth (v2: Q-in-reg, double-buffer) --
// grid = 256 blocks (2 matrices x 128 Q-blocks), block = 512 threads (8 waves)
// Wave w: QK^T rows (w&3)*16, cols (w>>2)*32; PV rows (w&3)*16, d (w>>2)*128.
// Pipeline per iter: [issue global loads t+1] -> QK -> exp/P -> barrier1 ->
//                    PV -> [ds_write t+1 -> buf^1] -> barrier2.
__global__ __launch_bounds__(512) void k_flash(
    const unsigned short* __restrict__ Xh,   // [2][8192][256] bf16
    const unsigned short* __restrict__ Xht,  // [2][256][8192] bf16
    float* __restrict__ Xf)                  // [2][8192][256] f32; overwritten with Y
{
    __shared__ unsigned char Kls[2][64 * 512];    // 2 x 32KB, XOR-swizzled rows
    __shared__ unsigned char Vtls[2][256 * 128];  // 2 x 32KB: d-major, 64 kv per row
    __shared__ unsigned char Pls[64 * 128];       // 8KB: 64 rows x 64 bf16
    __shared__ float lsum_sh[2][QB];
    __shared__ float nrm_sh[2][QB];

    const int tid = threadIdx.x;
    const int lane = tid & 63;
    const int w = tid >> 6;
    const int wrg = (w & 3) * 16;     // row-group base within Q tile
    const int wh = w >> 2;            // half id
    const int m = blockIdx.x >> 7;
    const int q0 = (blockIdx.x & 127) * QB;

    const unsigned short* Xm  = Xh  + (size_t)m * B_ROWS * D_DIM;
    const unsigned short* Xtm = Xht + (size_t)m * D_DIM * B_ROWS;
    float* Xfm = Xf + (size_t)m * B_ROWS * D_DIM;

    // ---- Q fragments in registers (one-time; A-frag layout for 16x16x32) ----
    bf16x8 qf[8];
    {
        const unsigned short* qb = Xm + (size_t)(q0 + wrg + (lane & 15)) * D_DIM
                                      + (lane >> 4) * 8;
        #pragma unroll
        for (int kk = 0; kk < 8; ++kk)
            qf[kk] = *(const bf16x8*)(qb + kk * 32);
    }

    // ---- prologue: stage tile 0 into buffer 0 --------------------------------
    float4 kr[4], vr[4];
    #pragma unroll
    for (int it = 0; it < 4; ++it) {
        const int c = it * 512 + tid;
        kr[it] = *(const float4*)(Xm  + (size_t)(c >> 5) * D_DIM  + (c & 31) * 8);
        vr[it] = *(const float4*)(Xtm + (size_t)(c >> 3) * B_ROWS + (c & 7) * 8);
    }
    #pragma unroll
    for (int it = 0; it < 4; ++it) {
        const int c = it * 512 + tid;
        const int row = c >> 5, dch = c & 31;
        *(float4*)(&Kls[0][row * 512 + ((dch * 16) ^ ((row & 7) << 4))]) = kr[it];
        const int d = c >> 3, kc = c & 7;
        *(float4*)(&Vtls[0][d * 128 + ((kc * 16) ^ ((d & 7) << 4))]) = vr[it];
    }
    __syncthreads();

    f32x4 o[8];
    #pragma unroll
    for (int i = 0; i < 8; ++i) o[i] = (f32x4){0.f, 0.f, 0.f, 0.f};
    float lsum[4] = {0.f, 0.f, 0.f, 0.f};
    const int cfbase = wh * 32;
    const int dbase  = wh * 128;
    int cur = 0;

    for (int kt = 0; kt < NT; ++kt) {
        // ---- issue global loads for tile kt+1 (hidden under QK+exp+PV) ------
        const int kvn = (kt + 1) * KB;
        if (kt + 1 < NT) {
            #pragma unroll
            for (int it = 0; it < 4; ++it) {
                const int c = it * 512 + tid;
                kr[it] = *(const float4*)(Xm  + (size_t)(kvn + (c >> 5)) * D_DIM + (c & 31) * 8);
                vr[it] = *(const float4*)(Xtm + (size_t)(c >> 3) * B_ROWS + kvn + (c & 7) * 8);
            }
        }

        // ---- QK^T: S[16 x 32] for this wave (A from registers) --------------
        f32x4 s0 = {0.f,0.f,0.f,0.f}, s1 = {0.f,0.f,0.f,0.f};
        const int brow0 = cfbase + (lane & 15);
        const int brow1 = brow0 + 16;
        #pragma unroll
        for (int kk = 0; kk < 8; ++kk) {
            const int kb = kk * 64 + ((lane >> 4) * 16);
            bf16x8 bK0 = *(const bf16x8*)(&Kls[cur][brow0 * 512 + (kb ^ ((brow0 & 7) << 4))]);
            bf16x8 bK1 = *(const bf16x8*)(&Kls[cur][brow1 * 512 + (kb ^ ((brow1 & 7) << 4))]);
            s0 = __builtin_amdgcn_mfma_f32_16x16x32_bf16(qf[kk], bK0, s0, 0, 0, 0);
            s1 = __builtin_amdgcn_mfma_f32_16x16x32_bf16(qf[kk], bK1, s1, 0, 0, 0);
        }
        // ---- P = exp(TAU*S); accumulate row-sums; write bf16 P to LDS -------
        #pragma unroll
        for (int i = 0; i < 4; ++i) {
            const float p0 = exp2f(s0[i] * TAU_LOG2E);
            const float p1 = exp2f(s1[i] * TAU_LOG2E);
            lsum[i] += p0 + p1;
            const int prow = wrg + (lane >> 4) * 4 + i;
            const int pc = cfbase + (lane & 15);
            *(unsigned short*)(Pls + prow * 128 + (( pc       * 2) ^ ((prow & 7) << 4))) = f2bf(p0);
            *(unsigned short*)(Pls + prow * 128 + (((pc + 16) * 2) ^ ((prow & 7) << 4))) = f2bf(p1);
        }
        __syncthreads();   // barrier1: P ready (and prev reads of buf[cur^1] long done)

        // ---- PV: O[16 x 128] += P[16 x 64] @ V[64 x 128] ---------------------
        #pragma unroll
        for (int kk = 0; kk < 2; ++kk) {
            const int kb = kk * 64 + ((lane >> 4) * 16);
            const int parow = wrg + (lane & 15);
            bf16x8 aP = *(const bf16x8*)(Pls + parow * 128 + (kb ^ ((parow & 7) << 4)));
            #pragma unroll
            for (int nf = 0; nf < 8; ++nf) {
                const int drow = dbase + nf * 16 + (lane & 15);
                bf16x8 bV = *(const bf16x8*)(&Vtls[cur][drow * 128 + (kb ^ ((drow & 7) << 4))]);
                o[nf] = __builtin_amdgcn_mfma_f32_16x16x32_bf16(aP, bV, o[nf], 0, 0, 0);
            }
        }

        // ---- write tile kt+1 into the other buffer --------------------------
        if (kt + 1 < NT) {
            #pragma unroll
            for (int it = 0; it < 4; ++it) {
                const int c = it * 512 + tid;
                const int row = c >> 5, dch = c & 31;
                *(float4*)(&Kls[cur ^ 1][row * 512 + ((dch * 16) ^ ((row & 7) << 4))]) = kr[it];
                const int d = c >> 3, kc = c & 7;
                *(float4*)(&Vtls[cur ^ 1][d * 128 + ((kc * 16) ^ ((d & 7) << 4))]) = vr[it];
            }
        }
        __syncthreads();   // barrier2: next tile staged; P reads complete
        cur ^= 1;
    }

    // ---- epilogue: softmax denominator, y = x - alpha*O/l, norm-rescale -----
    #pragma unroll
    for (int i = 0; i < 4; ++i) {
        float v = lsum[i];
        v += __shfl_xor(v, 1); v += __shfl_xor(v, 2);
        v += __shfl_xor(v, 4); v += __shfl_xor(v, 8);
        lsum[i] = v;
    }
    if ((lane & 15) == 0) {
        #pragma unroll
        for (int i = 0; i < 4; ++i)
            lsum_sh[wh][wrg + (lane >> 4) * 4 + i] = lsum[i];
    }
    __syncthreads();

    float nrm[4] = {0.f, 0.f, 0.f, 0.f};
    #pragma unroll
    for (int nf = 0; nf < 8; ++nf) {
        #pragma unroll
        for (int i = 0; i < 4; ++i) {
            const int rl = wrg + (lane >> 4) * 4 + i;
            const int col = dbase + nf * 16 + (lane & 15);
            const float x = Xfm[(size_t)(q0 + rl) * D_DIM + col];
            const float lt = lsum_sh[0][rl] + lsum_sh[1][rl];
            const float y = x - (ALPHA / lt) * o[nf][i];
            o[nf][i] = y;
            nrm[i] += y * y;
        }
    }
    #pragma unroll
    for (int i = 0; i < 4; ++i) {
        float v = nrm[i];
        v += __shfl_xor(v, 1); v += __shfl_xor(v, 2);
        v += __shfl_xor(v, 4); v += __shfl_xor(v, 8);
        nrm[i] = v;
    }
    if ((lane & 15) == 0) {
        #pragma unroll
        for (int i = 0; i < 4; ++i)
            nrm_sh[wh][wrg + (lane >> 4) * 4 + i] = nrm[i];
    }
    __syncthreads();
    #pragma unroll
    for (int nf = 0; nf < 8; ++nf) {
        #pragma unroll
        for (int i = 0; i < 4; ++i) {
            const int rl = wrg + (lane >> 4) * 4 + i;
            const int col = dbase + nf * 16 + (lane & 15);
            const float scale = sqrtf(nrm_sh[0][rl] + nrm_sh[1][rl]);  // * SHRINK_NORM(=1)
            Xfm[(size_t)(q0 + rl) * D_DIM + col] = o[nf][i] * scale;
        }
    }
}

// ---------------- Kernel C: loss = mean(log1p(exp(-dot(fu,fp)))) -------------
// v2: per-block reduction -> 256 atomics total (was 8192 same-address atomics)
__global__ __launch_bounds__(256) void k_loss(
    const float* __restrict__ Yu, const float* __restrict__ Yp,
    float* __restrict__ out)
{
    __shared__ float part[4];
    const int w = threadIdx.x >> 6;
    const int lane = threadIdx.x & 63;
    float acc = 0.0f;
    #pragma unroll
    for (int r = 0; r < 8; ++r) {
        const int row = blockIdx.x * 32 + w * 8 + r;
        const float4 a = *(const float4*)(Yu + (size_t)row * D_DIM + lane * 4);
        const float4 b = *(const float4*)(Yp + (size_t)row * D_DIM + lane * 4);
        float dot = a.x*b.x + a.y*b.y + a.z*b.z + a.w*b.w;
        #pragma unroll
        for (int mask = 32; mask; mask >>= 1) dot += __shfl_xor(dot, mask);
        if (lane == 0) acc += log1pf(expf(-dot));   // = -log(sigmoid(dot))
    }
    if (lane == 0) part[w] = acc;
    __syncthreads();
    if (threadIdx.x == 0) {
        const float s = part[0] + part[1] + part[2] + part[3];
        atomicAdd(out, s * (1.0f / 8192.0f));
    }
}

extern "C" void kernel_launch(void* const* d_in, const int* in_sizes, int n_in,
                              void* d_out, int out_size, void* d_ws, size_t ws_size,
                              hipStream_t stream) {
    const float* ue = (const float*)d_in[0];
    const float* ie = (const float*)d_in[1];
    const int*   u  = (const int*)d_in[2];
    const int*   p  = (const int*)d_in[3];
    float* out = (float*)d_out;

    char* ws = (char*)d_ws;
    float* Xf            = (float*)ws;                              // 16 MB: [2][8192][256] f32 (becomes Y)
    unsigned short* Xh   = (unsigned short*)(ws + (16u << 20));     //  8 MB: [2][8192][256] bf16
    unsigned short* Xht  = (unsigned short*)(ws + (24u << 20));     //  8 MB: [2][256][8192] bf16

    k_gather_norm<<<4096, 256, 0, stream>>>(ue, ie, u, p, Xf, Xh, out);
    k_transpose <<<1024, 256, 0, stream>>>(Xh, Xht);
    k_flash     <<<256, 512, 0, stream>>>(Xh, Xht, Xf);
    k_loss      <<<256, 256, 0, stream>>>(Xf, Xf + (size_t)B_ROWS * D_DIM, out);
}

// Round 4
// 411.032 us; speedup vs baseline: 1.7781x; 1.7781x over previous
//
#include <hip/hip_runtime.h>
#include <hip/hip_bf16.h>

#define B_ROWS 8192
#define D_DIM  256
#define QB     64
#define KB     64
#define NT     (B_ROWS / KB)
#define ALPHA  0.8f
// TAU * log2(e) = 3.0 * 1.4426950408889634
#define TAU_LOG2E 4.328085122666890f

typedef __attribute__((ext_vector_type(8))) short bf16x8;
typedef __attribute__((ext_vector_type(4))) float f32x4;
typedef __attribute__((ext_vector_type(4))) unsigned short ushort4v;

__device__ inline unsigned short f2bf(float f) {
    unsigned int u = __builtin_bit_cast(unsigned int, f);
    u += 0x7FFF + ((u >> 16) & 1);   // RNE (finite values)
    return (unsigned short)(u >> 16);
}

// global -> LDS DMA, 16B per lane. LDS dest = wave-uniform base + lane*16
// (linear); the swizzle is applied to the per-lane GLOBAL source instead.
__device__ inline void gl_lds16(const void* g, void* l) {
    __builtin_amdgcn_global_load_lds(
        (const __attribute__((address_space(1))) unsigned int*)g,
        (__attribute__((address_space(3))) unsigned int*)l, 16, 0, 0);
}

// raw barrier that drains only LDS ops (DMA prefetch stays in flight)
__device__ inline void barrier_lgkm() {
    asm volatile("s_waitcnt lgkmcnt(0)" ::: "memory");
    __builtin_amdgcn_s_barrier();
    asm volatile("" ::: "memory");
}
// end-of-iter barrier: staging DMAs + all LDS reads complete
__device__ inline void barrier_all() {
    asm volatile("s_waitcnt vmcnt(0) lgkmcnt(0)" ::: "memory");
    __builtin_amdgcn_s_barrier();
    asm volatile("" ::: "memory");
}

// ---------------- Kernel A: gather + row-normalize, emit f32 + bf16 copies --
__global__ __launch_bounds__(256) void k_gather_norm(
    const float* __restrict__ ue, const float* __restrict__ ie,
    const int* __restrict__ u, const int* __restrict__ p,
    float* __restrict__ Xf, unsigned short* __restrict__ Xh,
    float* __restrict__ out)
{
    const int b = blockIdx.x * 4 + (threadIdx.x >> 6);   // 0..16383
    const int lane = threadIdx.x & 63;
    if (b == 0 && lane == 0) out[0] = 0.0f;   // init accumulator (d_out is poisoned)
    const int m = b >> 13;
    const int r = b & 8191;
    const float* src = (m == 0) ? (ue + (size_t)u[r] * D_DIM)
                                : (ie + (size_t)p[r] * D_DIM);
    float4 v = ((const float4*)src)[lane];
    float ss = v.x*v.x + v.y*v.y + v.z*v.z + v.w*v.w;
    #pragma unroll
    for (int mask = 32; mask; mask >>= 1) ss += __shfl_xor(ss, mask);
    const float inv = 1.0f / sqrtf(ss);
    v.x *= inv; v.y *= inv; v.z *= inv; v.w *= inv;
    const size_t off = (size_t)(m * B_ROWS + r) * D_DIM + lane * 4;
    *(float4*)(Xf + off) = v;
    ushort4v h = { f2bf(v.x), f2bf(v.y), f2bf(v.z), f2bf(v.w) };
    *(ushort4v*)(Xh + off) = h;
}

// ---------------- Kernel T: bf16 transpose [2][8192][256] -> [2][256][8192] --
__global__ __launch_bounds__(256) void k_transpose(
    const unsigned short* __restrict__ Xh, unsigned short* __restrict__ Xht)
{
    __shared__ unsigned short tile[64 * 84];
    const int bid = blockIdx.x;                // 0..1023
    const int m = bid >> 9;
    const int t = bid & 511;
    const int rt = t >> 2, ct = t & 3;
    const int r0 = rt * 64, c0 = ct * 64;
    const int tid = threadIdx.x;
    const unsigned short* src = Xh + (size_t)m * B_ROWS * D_DIM;
    unsigned short* dst = Xht + (size_t)m * D_DIM * B_ROWS;
    #pragma unroll
    for (int ph = 0; ph < 2; ++ph) {
        const int row = ph * 32 + (tid >> 3);
        const int ch = tid & 7;
        const unsigned short* s = src + (size_t)(r0 + row) * D_DIM + c0 + ch * 8;
        ushort4v a = *(const ushort4v*)s;
        ushort4v b = *(const ushort4v*)(s + 4);
        *(ushort4v*)(&tile[row * 84 + ch * 8]) = a;
        *(ushort4v*)(&tile[row * 84 + ch * 8 + 4]) = b;
    }
    __syncthreads();
    #pragma unroll
    for (int ph = 0; ph < 2; ++ph) {
        const int d = ph * 32 + (tid >> 3);
        const int kc = tid & 7;
        ushort4v lo = { tile[(kc*8+0)*84 + d], tile[(kc*8+1)*84 + d],
                        tile[(kc*8+2)*84 + d], tile[(kc*8+3)*84 + d] };
        ushort4v hi = { tile[(kc*8+4)*84 + d], tile[(kc*8+5)*84 + d],
                        tile[(kc*8+6)*84 + d], tile[(kc*8+7)*84 + d] };
        unsigned short* o = dst + (size_t)(c0 + d) * B_ROWS + r0 + kc * 8;
        *(ushort4v*)o = lo;
        *(ushort4v*)(o + 4) = hi;
    }
}

// ---------------- Kernel B: flash spec-smooth v3 -----------------------------
// grid = 256 blocks (2 matrices x 128 Q-blocks), 512 threads (8 waves, 2Mx4N).
// Wave (wm=w>>2, wn=w&3):
//   QK: S rows wm*32..+31 (Q in regs), kv-cols wn*16..+15  -> K read 2x only
//   PV: O rows wm*32..+31, d-cols wn*64..+63               -> V read 2x only
// Staging: global_load_lds (16B) with pre-swizzled global source, linear LDS
// dest; double-buffered; DMAs issued at iter top, drained at end barrier only.
__global__ __launch_bounds__(512, 2) void k_flash(
    const unsigned short* __restrict__ Xh,   // [2][8192][256] bf16
    const unsigned short* __restrict__ Xht,  // [2][256][8192] bf16
    float* __restrict__ Xf)                  // [2][8192][256] f32; overwritten with Y
{
    __shared__ unsigned char Kls[2][64 * 512];    // 2 x 32KB, 16B-XOR-swizzled rows
    __shared__ unsigned char Vtls[2][256 * 128];  // 2 x 32KB: d-major, 64 kv per row
    __shared__ unsigned char Pls[64 * 128];       // 8KB: 64 q-rows x 64 kv bf16
    __shared__ float lsum_sh[4][QB];
    __shared__ float nrm_sh[4][QB];

    const int tid = threadIdx.x;
    const int lane = tid & 63;
    const int w = tid >> 6;
    const int wm = w >> 2;            // 0..1: q-row group (32 rows)
    const int wn = w & 3;             // 0..3: QK col-group / PV d-group
    const int m = blockIdx.x >> 7;
    const int q0 = (blockIdx.x & 127) * QB;

    const unsigned short* Xm  = Xh  + (size_t)m * B_ROWS * D_DIM;
    const unsigned short* Xtm = Xht + (size_t)m * D_DIM * B_ROWS;
    float* Xfm = Xf + (size_t)m * B_ROWS * D_DIM;

    // ---- Q fragments in registers: rows wm*32+mi*16+(lane&15) ---------------
    bf16x8 qf[2][8];
    #pragma unroll
    for (int mi = 0; mi < 2; ++mi) {
        const unsigned short* qb = Xm + (size_t)(q0 + wm*32 + mi*16 + (lane & 15)) * D_DIM
                                      + (lane >> 4) * 8;
        #pragma unroll
        for (int kk = 0; kk < 8; ++kk)
            qf[mi][kk] = *(const bf16x8*)(qb + kk * 32);
    }

    // ---- DMA staging geometry (per wave: 4 x 1KB chunks each for K and V) ---
    // K chunk: rows chunk*2+(lane>>5); 16B unit col16=lane&31 holds d-chunk
    //          col16^(row&7)  (inverse of the read-side XOR swizzle).
    // V chunk: d-rows chunk*8+(lane>>3); unit kc16=lane&7 holds kv-chunk
    //          kc16^(d&7).
    const int kchunk0 = w * 4;
    const int krow_l  = (lane >> 5);
    const int kcol16  = lane & 31;
    const int vd_l    = (lane >> 3);
    const int vkc16   = lane & 7;

    // ---- prologue: stage tile 0 into buffer 0 -------------------------------
    #pragma unroll
    for (int it = 0; it < 4; ++it) {
        const int chunk = kchunk0 + it;
        const int krow = chunk * 2 + krow_l;
        const int kdch = kcol16 ^ (krow & 7);
        gl_lds16(Xm + (size_t)krow * D_DIM + kdch * 8, &Kls[0][chunk * 1024]);
        const int vd = chunk * 8 + vd_l;
        const int vkc = vkc16 ^ (vd & 7);
        gl_lds16(Xtm + (size_t)vd * B_ROWS + vkc * 8, &Vtls[0][chunk * 1024]);
    }
    barrier_all();

    f32x4 o[2][4];
    #pragma unroll
    for (int mi = 0; mi < 2; ++mi)
        #pragma unroll
        for (int nf = 0; nf < 4; ++nf) o[mi][nf] = (f32x4){0.f, 0.f, 0.f, 0.f};
    float lsum[2][4] = {{0.f,0.f,0.f,0.f},{0.f,0.f,0.f,0.f}};
    int cur = 0;

    for (int kt = 0; kt < NT; ++kt) {
        const int nxt = cur ^ 1;
        // ---- issue DMA for tile kt+1 (in flight across the P barrier) -------
        if (kt + 1 < NT) {
            const int kvn = (kt + 1) * KB;
            #pragma unroll
            for (int it = 0; it < 4; ++it) {
                const int chunk = kchunk0 + it;
                const int krow = chunk * 2 + krow_l;
                const int kdch = kcol16 ^ (krow & 7);
                gl_lds16(Xm + (size_t)(kvn + krow) * D_DIM + kdch * 8,
                         &Kls[nxt][chunk * 1024]);
                const int vd = chunk * 8 + vd_l;
                const int vkc = vkc16 ^ (vd & 7);
                gl_lds16(Xtm + (size_t)vd * B_ROWS + kvn + vkc * 8,
                         &Vtls[nxt][chunk * 1024]);
            }
        }

        // ---- QK^T: S[32 x 16] per wave (Q regs x K LDS) ---------------------
        f32x4 s0 = {0.f,0.f,0.f,0.f}, s1 = {0.f,0.f,0.f,0.f};
        {
            const int brow = wn * 16 + (lane & 15);
            const unsigned char* kbase = &Kls[cur][brow * 512];
            const int bswz = (brow & 7) << 4;
            #pragma unroll
            for (int kk = 0; kk < 8; ++kk) {
                const int kb = kk * 64 + ((lane >> 4) * 16);
                bf16x8 bK = *(const bf16x8*)(kbase + (kb ^ bswz));
                s0 = __builtin_amdgcn_mfma_f32_16x16x32_bf16(qf[0][kk], bK, s0, 0, 0, 0);
                s1 = __builtin_amdgcn_mfma_f32_16x16x32_bf16(qf[1][kk], bK, s1, 0, 0, 0);
            }
        }
        // ---- P = exp(TAU*S); row-sum partials; bf16 P to LDS ----------------
        #pragma unroll
        for (int i = 0; i < 4; ++i) {
            const float p0 = exp2f(s0[i] * TAU_LOG2E);
            const float p1 = exp2f(s1[i] * TAU_LOG2E);
            lsum[0][i] += p0;
            lsum[1][i] += p1;
            const int pr0 = wm*32 + (lane >> 4) * 4 + i;
            const int pr1 = pr0 + 16;
            const int pc2 = (wn*16 + (lane & 15)) * 2;
            *(unsigned short*)(Pls + pr0*128 + (pc2 ^ ((pr0 & 7) << 4))) = f2bf(p0);
            *(unsigned short*)(Pls + pr1*128 + (pc2 ^ ((pr1 & 7) << 4))) = f2bf(p1);
        }
        barrier_lgkm();   // P visible; prefetch DMAs NOT drained

        // ---- PV: O[32 x 64] += P[32 x 64] @ V[64 x 64-d-slice] --------------
        bf16x8 aP[2][2];
        #pragma unroll
        for (int mi = 0; mi < 2; ++mi)
            #pragma unroll
            for (int ks = 0; ks < 2; ++ks) {
                const int ar = wm*32 + mi*16 + (lane & 15);
                const int akb = ks*64 + ((lane >> 4) * 16);
                aP[mi][ks] = *(const bf16x8*)(Pls + ar*128 + (akb ^ ((ar & 7) << 4)));
            }
        #pragma unroll
        for (int ks = 0; ks < 2; ++ks) {
            #pragma unroll
            for (int nf = 0; nf < 4; ++nf) {
                const int dr = wn*64 + nf*16 + (lane & 15);
                const int kb2 = ks*64 + ((lane >> 4) * 16);
                bf16x8 bV = *(const bf16x8*)(&Vtls[cur][dr*128 + (kb2 ^ ((dr & 7) << 4))]);
                o[0][nf] = __builtin_amdgcn_mfma_f32_16x16x32_bf16(aP[0][ks], bV, o[0][nf], 0, 0, 0);
                o[1][nf] = __builtin_amdgcn_mfma_f32_16x16x32_bf16(aP[1][ks], bV, o[1][nf], 0, 0, 0);
            }
        }

        barrier_all();    // DMAs landed; all LDS reads of cur/P complete
        cur = nxt;
    }

    // ---- epilogue -----------------------------------------------------------
    // 1) publish per-wn partial row-sums of P (each wave owns 16 kv-cols)
    #pragma unroll
    for (int mi = 0; mi < 2; ++mi)
        #pragma unroll
        for (int i = 0; i < 4; ++i) {
            float v = lsum[mi][i];
            v += __shfl_xor(v, 1); v += __shfl_xor(v, 2);
            v += __shfl_xor(v, 4); v += __shfl_xor(v, 8);
            if ((lane & 15) == 0)
                lsum_sh[wn][wm*32 + mi*16 + (lane >> 4)*4 + i] = v;
        }
    __syncthreads();

    // 2) y = x - alpha*O/l ; accumulate row-norm partials (this wave's 64 cols)
    float nrm[2][4] = {{0.f,0.f,0.f,0.f},{0.f,0.f,0.f,0.f}};
    #pragma unroll
    for (int mi = 0; mi < 2; ++mi)
        #pragma unroll
        for (int nf = 0; nf < 4; ++nf)
            #pragma unroll
            for (int i = 0; i < 4; ++i) {
                const int row = wm*32 + mi*16 + (lane >> 4)*4 + i;
                const int col = wn*64 + nf*16 + (lane & 15);
                const float x = Xfm[(size_t)(q0 + row) * D_DIM + col];
                const float lt = lsum_sh[0][row] + lsum_sh[1][row]
                               + lsum_sh[2][row] + lsum_sh[3][row];
                const float y = x - (ALPHA / lt) * o[mi][nf][i];
                o[mi][nf][i] = y;
                nrm[mi][i] += y * y;
            }
    #pragma unroll
    for (int mi = 0; mi < 2; ++mi)
        #pragma unroll
        for (int i = 0; i < 4; ++i) {
            float v = nrm[mi][i];
            v += __shfl_xor(v, 1); v += __shfl_xor(v, 2);
            v += __shfl_xor(v, 4); v += __shfl_xor(v, 8);
            if ((lane & 15) == 0)
                nrm_sh[wn][wm*32 + mi*16 + (lane >> 4)*4 + i] = v;
        }
    __syncthreads();

    // 3) rescale by ||y|| (SHRINK_NORM == 1) and store
    #pragma unroll
    for (int mi = 0; mi < 2; ++mi)
        #pragma unroll
        for (int nf = 0; nf < 4; ++nf)
            #pragma unroll
            for (int i = 0; i < 4; ++i) {
                const int row = wm*32 + mi*16 + (lane >> 4)*4 + i;
                const int col = wn*64 + nf*16 + (lane & 15);
                const float scale = sqrtf(nrm_sh[0][row] + nrm_sh[1][row]
                                        + nrm_sh[2][row] + nrm_sh[3][row]);
                Xfm[(size_t)(q0 + row) * D_DIM + col] = o[mi][nf][i] * scale;
            }
}

// ---------------- Kernel C: loss = mean(log1p(exp(-dot(fu,fp)))) -------------
__global__ __launch_bounds__(256) void k_loss(
    const float* __restrict__ Yu, const float* __restrict__ Yp,
    float* __restrict__ out)
{
    __shared__ float part[4];
    const int w = threadIdx.x >> 6;
    const int lane = threadIdx.x & 63;
    float acc = 0.0f;
    #pragma unroll
    for (int r = 0; r < 8; ++r) {
        const int row = blockIdx.x * 32 + w * 8 + r;
        const float4 a = *(const float4*)(Yu + (size_t)row * D_DIM + lane * 4);
        const float4 b = *(const float4*)(Yp + (size_t)row * D_DIM + lane * 4);
        float dot = a.x*b.x + a.y*b.y + a.z*b.z + a.w*b.w;
        #pragma unroll
        for (int mask = 32; mask; mask >>= 1) dot += __shfl_xor(dot, mask);
        if (lane == 0) acc += log1pf(expf(-dot));   // = -log(sigmoid(dot))
    }
    if (lane == 0) part[w] = acc;
    __syncthreads();
    if (threadIdx.x == 0) {
        const float s = part[0] + part[1] + part[2] + part[3];
        atomicAdd(out, s * (1.0f / 8192.0f));
    }
}

extern "C" void kernel_launch(void* const* d_in, const int* in_sizes, int n_in,
                              void* d_out, int out_size, void* d_ws, size_t ws_size,
                              hipStream_t stream) {
    const float* ue = (const float*)d_in[0];
    const float* ie = (const float*)d_in[1];
    const int*   u  = (const int*)d_in[2];
    const int*   p  = (const int*)d_in[3];
    float* out = (float*)d_out;

    char* ws = (char*)d_ws;
    float* Xf            = (float*)ws;                              // 16 MB: [2][8192][256] f32 (becomes Y)
    unsigned short* Xh   = (unsigned short*)(ws + (16u << 20));     //  8 MB: [2][8192][256] bf16
    unsigned short* Xht  = (unsigned short*)(ws + (24u << 20));     //  8 MB: [2][256][8192] bf16

    k_gather_norm<<<4096, 256, 0, stream>>>(ue, ie, u, p, Xf, Xh, out);
    k_transpose <<<1024, 256, 0, stream>>>(Xh, Xht);
    k_flash     <<<256, 512, 0, stream>>>(Xh, Xht, Xf);
    k_loss      <<<256, 256, 0, stream>>>(Xf, Xf + (size_t)B_ROWS * D_DIM, out);
}